// Round 9
// baseline (95.637 us; speedup 1.0000x reference)
//
#include <hip/hip_runtime.h>

#define P_POSES   32
#define A_ATOMS   4096
#define T_HASH    1048576
#define EPSF      1e-8f
#define NBKT      256          // 32 poses x 8 key slices
#define KS        3            // sub-blocks per bucket in kB (grid = 768)
#define ITEMS     4
#define CHUNK     (256*ITEMS)  // 1024 items per kA2 block

typedef int   int4v   __attribute__((ext_vector_type(4)));
typedef float float4v __attribute__((ext_vector_type(4)));

// ---------------- init: bucket cursors + output ----------------
__global__ __launch_bounds__(256) void k_init(int* __restrict__ cursor,
                                              float* __restrict__ out, int cap) {
    const int t = threadIdx.x;
    cursor[t] = t * cap;
    if (t < P_POSES) out[t] = 0.0f;
}

// ---------------- kA2: ballot-ranked bucketing by (pose, key>>17) ----------------
__global__ __launch_bounds__(256) void kA2_bucket(const int4v* __restrict__ atoms,
                                                  const int*   __restrict__ pose,
                                                  const int*   __restrict__ uids,
                                                  int*         __restrict__ cursor,
                                                  int4v*       __restrict__ rec,
                                                  int S, int cap) {
    __shared__ int cnt[NBKT];
    __shared__ int gbase[NBKT];
    const int tid = threadIdx.x, lane = tid & 63;
    cnt[tid] = 0;
    __syncthreads();

    const int s0 = blockIdx.x * CHUNK;
    bool  act[ITEMS]; int4v a[ITEMS]; int pp[ITEMS];

    // phase 1: coalesced stream loads
    #pragma unroll
    for (int it = 0; it < ITEMS; ++it) {
        const int s = s0 + it * 256 + tid;
        act[it] = s < S;
        if (act[it]) {
            a[it]  = __builtin_nontemporal_load(&atoms[s]);
            pp[it] = __builtin_nontemporal_load(&pose[s]);
        } else { a[it] = (int4v){0,0,0,0}; pp[it] = 255; }
    }

    // phase 2: uid gathers + key + record packing (all loads issued together)
    int4v rc[ITEMS]; int bk[ITEMS]; int ss[ITEMS];
    #pragma unroll
    for (int it = 0; it < ITEMS; ++it) {
        const int4v aa = a[it];
        const bool v0 = aa.x >= 0, v1 = aa.y >= 0, v2 = aa.z >= 0, v3 = aa.w >= 0;
        const int  i0 = v0 ? aa.x : 0;
        const int  i1 = v1 ? aa.y : 0;
        const int  i2 = v2 ? aa.z : 0;
        const int  i3 = v3 ? aa.w : 0;
        const int  nv = (int)v0 + (int)v1 + (int)v2 + (int)v3;
        const int  p  = act[it] ? pp[it] : 0;
        const int* __restrict__ urow = uids + p * A_ATOMS;
        unsigned key = (v0 ? (unsigned)urow[i0] : 0u)
                     + (v1 ? (unsigned)urow[i1] : 0u)
                     + (v2 ? (unsigned)urow[i2] : 0u)
                     + (v3 ? (unsigned)urow[i3] : 0u);
        key &= (unsigned)(T_HASH - 1);
        int4v r;
        r.x = i0 | (i1 << 16);
        r.y = i2 | (i3 << 16);
        r.z = (int)(key | ((unsigned)nv << 20));
        r.w = 0;
        rc[it] = r;
        ss[it] = act[it] ? (int)(key >> 17) : 8;      // sentinel slice never balloted
        bk[it] = ((pp[it] & 31) << 3) | (ss[it] & 7); // valid only when act
    }

    // phase 3: wave ballot ranking + one LDS atomic per (wave, bucket)
    int ofs[ITEMS];
    #pragma unroll
    for (int it = 0; it < ITEMS; ++it) {
        unsigned long long pm = 0ull, sm = 0ull;
        #pragma unroll
        for (int q = 0; q < 32; ++q) {
            const unsigned long long m = __ballot(act[it] && pp[it] == q);
            if (pp[it] == q) pm = m;
        }
        #pragma unroll
        for (int q = 0; q < 8; ++q) {
            const unsigned long long m = __ballot(act[it] && ss[it] == q);
            if (ss[it] == q) sm = m;
        }
        const unsigned long long gm = pm & sm;   // lanes in MY (pose,slice) group
        const int rank = __popcll(gm & ((1ull << lane) - 1ull));
        const int ldr  = (int)__ffsll((unsigned long long)gm) - 1;
        int wb = 0;
        if (act[it] && lane == ldr) wb = atomicAdd(&cnt[bk[it]], __popcll(gm));
        wb = __shfl(wb, (ldr < 0) ? 0 : ldr, 64);
        ofs[it] = wb + rank;
    }
    __syncthreads();

    // phase 4: block-level global reservation
    { const int c = cnt[tid]; gbase[tid] = c ? atomicAdd(&cursor[tid], c) : 0; }
    __syncthreads();

    // phase 5: scattered record writes (no dependency, fire and forget)
    #pragma unroll
    for (int it = 0; it < ITEMS; ++it)
        if (act[it]) rec[(size_t)gbase[bk[it]] + ofs[it]] = rc[it];
}

// ---------------- energy from loaded values ----------------
__device__ __forceinline__ float item_energy(
    float p0x, float p0y, float p0z, float p1x, float p1y, float p1z,
    float p2x, float p2y, float p2z, float p3x, float p3y, float p3z,
    float K, float x0, float period, int nv)
{
    // bond
    const float dbx = p1x - p0x, dby = p1y - p0y, dbz = p1z - p0z;
    const float d  = sqrtf(dbx*dbx + dby*dby + dbz*dbz + EPSF);
    const float db = d - x0;
    const float e_bond = K * db * db;

    // angle (u = p0-p1, v = p2-p1)
    const float vx = p2x - p1x, vy = p2y - p1y, vz = p2z - p1z;
    const float uv = dbx*vx + dby*vy + dbz*vz;         // (p0-p1)·v = -(db·v)
    const float uu = dbx*dbx + dby*dby + dbz*dbz;
    const float vv = vx*vx + vy*vy + vz*vz;
    float cosang = (-uv) / (sqrtf(uu + EPSF) * sqrtf(vv + EPSF));
    cosang = fminf(fmaxf(cosang, -0.999999f), 0.999999f);
    const float theta = acosf(cosang);
    const float da = theta - x0;
    const float e_angle = K * da * da;

    // torsion
    const float b3x = p3x - p2x, b3y = p3y - p2y, b3z = p3z - p2z;
    const float n1x = dby*vz - dbz*vy;
    const float n1y = dbz*vx - dbx*vz;
    const float n1z = dbx*vy - dby*vx;
    const float n2x = vy*b3z - vz*b3y;
    const float n2y = vz*b3x - vx*b3z;
    const float n2z = vx*b3y - vy*b3x;
    const float b2inv = 1.0f / sqrtf(vv + EPSF);
    const float bnx = vx*b2inv, bny = vy*b2inv, bnz = vz*b2inv;
    const float m1x = n1y*bnz - n1z*bny;
    const float m1y = n1z*bnx - n1x*bnz;
    const float m1z = n1x*bny - n1y*bnx;
    const float sy = m1x*n2x + m1y*n2y + m1z*n2z;
    const float sx = n1x*n2x + n1y*n2y + n1z*n2z + EPSF;
    const float phi = atan2f(sy, sx);
    const float e_tors = K * (1.0f + cosf(period*phi - x0));

    return (nv == 2) ? e_bond : ((nv == 3) ? e_angle : e_tors);
}

// ---------------- kB: per-(pose,slice) scoring, 2-way ILP ----------------
__global__ __launch_bounds__(256) void kB_score(const float* __restrict__ coords,
                                                const float* __restrict__ hv,
                                                const int*   __restrict__ cursor,
                                                const int4v* __restrict__ rec,
                                                float*       __restrict__ out, int cap) {
    __shared__ float sC[A_ATOMS * 3];   // 48 KB

    const int blk  = blockIdx.x;
    const int b    = blk & 255;               // (pose<<3)|slice ; slice = blk&7 -> XCD affinity
    const int ks   = blk >> 8;                // 0..KS-1
    const int pose = b >> 3;
    const int tid  = threadIdx.x;

    {   // stage this pose's coords (coalesced float4)
        const float4v* src = (const float4v*)(coords + (size_t)pose * (A_ATOMS * 3));
        float4v* dst = (float4v*)sC;
        #pragma unroll 4
        for (int i = tid; i < (A_ATOMS * 3) / 4; i += 256) dst[i] = src[i];
    }
    __syncthreads();

    const int base   = b * cap;
    const int end    = cursor[b];
    const int stride = KS * 256;
    float esum = 0.0f;

    for (int i = base + ks * 256 + tid; i < end; i += 2 * stride) {
        const int  j    = i + stride;
        const bool has1 = j < end;

        const int4v r0 = rec[i];
        const int4v r1 = has1 ? rec[j] : r0;

        const int a0i0 = r0.x & 0xFFFF, a0i1 = ((unsigned)r0.x) >> 16;
        const int a0i2 = r0.y & 0xFFFF, a0i3 = ((unsigned)r0.y) >> 16;
        const unsigned z0 = (unsigned)r0.z;
        const unsigned k0 = z0 & (unsigned)(T_HASH - 1);
        const int nv0 = (int)((z0 >> 20) & 7u);

        const int a1i0 = r1.x & 0xFFFF, a1i1 = ((unsigned)r1.x) >> 16;
        const int a1i2 = r1.y & 0xFFFF, a1i3 = ((unsigned)r1.y) >> 16;
        const unsigned z1 = (unsigned)r1.z;
        const unsigned k1 = z1 & (unsigned)(T_HASH - 1);
        const int nv1 = (int)((z1 >> 20) & 7u);

        // issue all global gathers first
        const float K0 = hv[3*(size_t)k0+0], x00 = hv[3*(size_t)k0+1], pr0 = hv[3*(size_t)k0+2];
        const float K1 = hv[3*(size_t)k1+0], x01 = hv[3*(size_t)k1+1], pr1 = hv[3*(size_t)k1+2];

        // issue all LDS reads
        const float q0p0x = sC[3*a0i0+0], q0p0y = sC[3*a0i0+1], q0p0z = sC[3*a0i0+2];
        const float q0p1x = sC[3*a0i1+0], q0p1y = sC[3*a0i1+1], q0p1z = sC[3*a0i1+2];
        const float q0p2x = sC[3*a0i2+0], q0p2y = sC[3*a0i2+1], q0p2z = sC[3*a0i2+2];
        const float q0p3x = sC[3*a0i3+0], q0p3y = sC[3*a0i3+1], q0p3z = sC[3*a0i3+2];
        const float q1p0x = sC[3*a1i0+0], q1p0y = sC[3*a1i0+1], q1p0z = sC[3*a1i0+2];
        const float q1p1x = sC[3*a1i1+0], q1p1y = sC[3*a1i1+1], q1p1z = sC[3*a1i1+2];
        const float q1p2x = sC[3*a1i2+0], q1p2y = sC[3*a1i2+1], q1p2z = sC[3*a1i2+2];
        const float q1p3x = sC[3*a1i3+0], q1p3y = sC[3*a1i3+1], q1p3z = sC[3*a1i3+2];

        const float e0 = item_energy(q0p0x,q0p0y,q0p0z, q0p1x,q0p1y,q0p1z,
                                     q0p2x,q0p2y,q0p2z, q0p3x,q0p3y,q0p3z,
                                     K0, x00, pr0, nv0);
        const float e1 = item_energy(q1p0x,q1p0y,q1p0z, q1p1x,q1p1y,q1p1z,
                                     q1p2x,q1p2y,q1p2z, q1p3x,q1p3y,q1p3z,
                                     K1, x01, pr1, nv1);
        esum += e0 + (has1 ? e1 : 0.0f);
    }

    #pragma unroll
    for (int off = 32; off > 0; off >>= 1) esum += __shfl_down(esum, off, 64);
    if ((tid & 63) == 0 && esum != 0.0f) atomicAdd(&out[pose], esum);
}

// ---------------- fallback (proven monolithic path) ----------------
__global__ __launch_bounds__(256) void fb_kernel(const float* __restrict__ coords,
                                                 const float* __restrict__ hv,
                                                 const int4v* __restrict__ atoms,
                                                 const int*   __restrict__ pose,
                                                 const int*   __restrict__ uids,
                                                 float* __restrict__ out, int S) {
    __shared__ float bins[P_POSES];
    if (threadIdx.x < P_POSES) bins[threadIdx.x] = 0.0f;
    __syncthreads();
    const int s = blockIdx.x * blockDim.x + threadIdx.x;
    if (s < S) {
        const int4v a = atoms[s];
        const int   p = pose[s];
        const bool v0 = a.x >= 0, v1 = a.y >= 0, v2 = a.z >= 0, v3 = a.w >= 0;
        const int  i0 = v0 ? a.x : 0, i1 = v1 ? a.y : 0, i2 = v2 ? a.z : 0, i3 = v3 ? a.w : 0;
        const int  nv = (int)v0 + (int)v1 + (int)v2 + (int)v3;
        const int* urow = uids + p * A_ATOMS;
        unsigned int key = (v0?(unsigned)urow[i0]:0u) + (v1?(unsigned)urow[i1]:0u)
                         + (v2?(unsigned)urow[i2]:0u) + (v3?(unsigned)urow[i3]:0u);
        key &= (unsigned)(T_HASH - 1);
        const float K = hv[3*key], x0 = hv[3*key+1], period = hv[3*key+2];
        const float* crow = coords + (size_t)p * (A_ATOMS * 3);
        const float e = item_energy(crow[i0*3],crow[i0*3+1],crow[i0*3+2],
                                    crow[i1*3],crow[i1*3+1],crow[i1*3+2],
                                    crow[i2*3],crow[i2*3+1],crow[i2*3+2],
                                    crow[i3*3],crow[i3*3+1],crow[i3*3+2],
                                    K, x0, period, nv);
        atomicAdd(&bins[p], e);
    }
    __syncthreads();
    if (threadIdx.x < P_POSES) {
        const float bsum = bins[threadIdx.x];
        if (bsum != 0.0f) atomicAdd(&out[threadIdx.x], bsum);
    }
}

extern "C" void kernel_launch(void* const* d_in, const int* in_sizes, int n_in,
                              void* d_out, int out_size, void* d_ws, size_t ws_size,
                              hipStream_t stream) {
    const float* coords = (const float*)d_in[0];
    const float* hv     = (const float*)d_in[1];
    const int4v* atoms  = (const int4v*)d_in[2];
    const int*   pose   = (const int*)d_in[3];
    const int*   uids   = (const int*)d_in[4];
    float* out = (float*)d_out;
    const int S = in_sizes[3];

    // bucket capacity: 1.4x mean (mean + ~30 sigma of multinomial spread)
    int cap = (int)(((long long)S / NBKT) * 7 / 5);
    cap = (cap + 63) & ~63;

    const size_t need = 4096 + (size_t)NBKT * cap * 16;

    if (ws_size < need) {
        hipMemsetAsync(out, 0, P_POSES * sizeof(float), stream);
        fb_kernel<<<(S + 255) / 256, 256, 0, stream>>>(coords, hv, atoms, pose, uids, out, S);
        return;
    }

    int*   cursor = (int*)d_ws;
    int4v* rec    = (int4v*)((char*)d_ws + 4096);

    k_init<<<1, 256, 0, stream>>>(cursor, out, cap);
    kA2_bucket<<<(S + CHUNK - 1) / CHUNK, 256, 0, stream>>>(atoms, pose, uids, cursor, rec, S, cap);
    kB_score<<<NBKT * KS, 256, 0, stream>>>(coords, hv, cursor, rec, out, cap);
}